// Round 1
// baseline (6454.359 us; speedup 1.0000x reference)
//
#include <hip/hip_runtime.h>
#include <hip/hip_bf16.h>

// Problem constants
#define BB 128
#define TT 1024
#define DD 3
#define HH 512
#define CC 3

#define NG 8      // batch groups
#define NCH 16    // h-chunks per group (producers per flag)
#define MB 16     // batch rows per group
#define HC 32     // h columns per chunk

typedef __attribute__((ext_vector_type(8))) __bf16 bf16x8;
typedef __attribute__((ext_vector_type(4))) float f32x4;

// Persistent RNN kernel. 128 blocks x 256 threads, ~91KB LDS -> 1 block/CU,
// all blocks co-resident (128 <= 256 CUs). Sync between the 16 chunk-owners of
// a batch group via per-(group,step) counters in d_ws (release/acquire, agent
// scope -> correct across XCDs).
__global__ __launch_bounds__(256, 1) void rnn_persist(
    const float* __restrict__ x,    // [B][T][D]
    const float* __restrict__ W,    // [H][H]
    const float* __restrict__ P,    // [H][D]
    const float* __restrict__ bv,   // [H]
    const float* __restrict__ Wz,   // [H][H]
    const float* __restrict__ Pz,   // [H][D]
    const float* __restrict__ bz,   // [H]
    float* __restrict__ hidden,     // [B][T][H] (inside d_out)
    unsigned* __restrict__ Rbuf,    // [2][B][H/2] u32 = bf16 pairs (in d_ws)
    int* __restrict__ cnt)          // [NG][TT+1] (in d_ws, pre-zeroed)
{
    __shared__ __bf16 Wl[64][520];   // rows 0..31 = Wz chunk, 32..63 = W chunk (pitch 520: bank-conflict pad)
    __shared__ __bf16 Ra[16][520];   // staged state tile, bf16
    __shared__ float  pre[16][65];   // MFMA output: [batch m][col n], n 0..31=z, 32..63=cand
    __shared__ float  rloc[16][33];  // f32 state for own chunk (exact recurrence path)
    __shared__ float  Pzl[32][3], Pvl[32][3], bzl[32], bvl[32];

    const int tid = threadIdx.x;
    const int bid = blockIdx.x;
    const int g   = bid & 7;         // batch group
    const int ch  = bid >> 3;        // h chunk
    const int h0  = ch * HC;
    const int b0  = g * MB;

    // ---- one-time staging: weights -> LDS bf16 ----
    for (int idx = tid; idx < 64 * 512; idx += 256) {
        int row = idx >> 9, col = idx & 511;
        float v = (row < 32) ? Wz[(h0 + row) * HH + col]
                             : W[(h0 + row - 32) * HH + col];
        Wl[row][col] = (__bf16)v;
    }
    if (tid < 32) {
        int hg = h0 + tid;
        for (int d = 0; d < 3; d++) {
            Pzl[tid][d] = Pz[hg * 3 + d];
            Pvl[tid][d] = (hg < HH / 2) ? P[hg * 3 + d] : 0.f;  // P_m: top half zeroed
        }
        bzl[tid] = bz[hg];
        bvl[tid] = bv[hg];
    }
    // init state: r0 = 0 (f32 local + bf16 global parity-0 slice)
    {
        int b = tid >> 4, hp = tid & 15;
        rloc[b][2 * hp] = 0.f;
        rloc[b][2 * hp + 1] = 0.f;
        unsigned* dst = Rbuf + (size_t)(b0 + b) * (HH / 2) + (h0 >> 1) + hp;
        __hip_atomic_store(dst, 0u, __ATOMIC_RELAXED, __HIP_MEMORY_SCOPE_AGENT);
    }
    __syncthreads();
    if (tid == 0)
        __hip_atomic_fetch_add(&cnt[g * (TT + 1)], 1, __ATOMIC_RELEASE, __HIP_MEMORY_SCOPE_AGENT);

    const int lane = tid & 63;
    const int wv   = tid >> 6;       // wave 0..3 -> output cols [wv*16, wv*16+16)
    const int frow = lane & 15;      // fragment index (m for A, n for B/D cols)
    const int q    = lane >> 4;      // quad 0..3

    const int eb  = tid >> 4;        // elementwise: batch row 0..15
    const int ehp = tid & 15;        // elementwise: h pair 0..15

    for (int t = 0; t < TT; t++) {
        // x for this step (flag-independent; issue before the spin)
        const float* xr = x + ((size_t)(b0 + eb) * TT + t) * DD;
        float x0 = xr[0], x1 = xr[1], x2 = xr[2];

        // wait for all 16 chunks of S_t
        if (tid == 0) {
            while (__hip_atomic_load(&cnt[g * (TT + 1) + t], __ATOMIC_ACQUIRE,
                                     __HIP_MEMORY_SCOPE_AGENT) < NCH)
                __builtin_amdgcn_s_sleep(1);
        }
        __syncthreads();

        // stage S_t (16 rows x 512 bf16 = 16KB) -> LDS
        {
            const uint4* src = (const uint4*)(Rbuf + (size_t)(t & 1) * BB * (HH / 2)
                                              + (size_t)b0 * (HH / 2));
            #pragma unroll
            for (int i = 0; i < 4; i++) {
                int j = tid + i * 256;          // 0..1023
                int row = j >> 6, c = j & 63;   // 64 uint4 per row
                uint4 v = src[row * 64 + c];
                *(uint4*)&Ra[row][c * 8] = v;
            }
        }
        __syncthreads();

        // MFMA: D[m][n] = sum_k Ra[m][k] * Wl[n][k]; one 16x16 tile per wave
        f32x4 acc = {0.f, 0.f, 0.f, 0.f};
        #pragma unroll
        for (int ks = 0; ks < 16; ks++) {
            bf16x8 af = *(const bf16x8*)&Ra[frow][ks * 32 + q * 8];
            bf16x8 bf = *(const bf16x8*)&Wl[wv * 16 + frow][ks * 32 + q * 8];
            acc = __builtin_amdgcn_mfma_f32_16x16x32_bf16(af, bf, acc, 0, 0, 0);
        }
        // C/D layout: col = lane&15, row = q*4 + r  (row=m batch, col=n)
        #pragma unroll
        for (int r = 0; r < 4; r++)
            pre[q * 4 + r][wv * 16 + frow] = acc[r];
        __syncthreads();

        // elementwise gates + state update; thread -> (batch eb, h pair ehp)
        float rn[2];
        #pragma unroll
        for (int e = 0; e < 2; e++) {
            int hl = 2 * ehp + e;
            float pz = pre[eb][hl]      + x0 * Pzl[hl][0] + x1 * Pzl[hl][1] + x2 * Pzl[hl][2] + bzl[hl];
            float pv = pre[eb][32 + hl] + x0 * Pvl[hl][0] + x1 * Pvl[hl][1] + x2 * Pvl[hl][2] + bvl[hl];
            float z    = 1.f / (1.f + __expf(-pz));
            float cand = 1.f / (1.f + __expf(-pv));
            float rp = rloc[eb][hl];
            rn[e] = (1.f - z) * rp + z * cand;
            rloc[eb][hl] = rn[e];
        }
        // publish bf16 pair to Rbuf[(t+1)&1]
        union { __bf16 h[2]; unsigned u; } pk;
        pk.h[0] = (__bf16)rn[0];
        pk.h[1] = (__bf16)rn[1];
        unsigned* dst = Rbuf + (size_t)((t + 1) & 1) * BB * (HH / 2)
                        + (size_t)(b0 + eb) * (HH / 2) + (h0 >> 1) + ehp;
        __hip_atomic_store(dst, pk.u, __ATOMIC_RELAXED, __HIP_MEMORY_SCOPE_AGENT);
        // hidden output (f32, exact state)
        float2 hv; hv.x = rn[0]; hv.y = rn[1];
        *(float2*)&hidden[((size_t)(b0 + eb) * TT + t) * HH + h0 + 2 * ehp] = hv;

        __syncthreads();  // drains vmcnt -> all stores globally visible before flag
        if (tid == 0)
            __hip_atomic_fetch_add(&cnt[g * (TT + 1) + t + 1], 1, __ATOMIC_RELEASE, __HIP_MEMORY_SCOPE_AGENT);
    }
}

// out[b][t][c] = hidden[b][t][:] . fc_W[c][:] + fc_b[c]   (HBM-bound, ~268MB read)
__global__ __launch_bounds__(256) void fc_kernel(
    const float* __restrict__ hidden, const float* __restrict__ fcW,
    const float* __restrict__ fcb, float* __restrict__ out)
{
    const int lane = threadIdx.x & 63;
    const int wid  = (blockIdx.x * blockDim.x + threadIdx.x) >> 6;
    const int nw   = (gridDim.x * blockDim.x) >> 6;

    float w0[8], w1[8], w2[8];
    #pragma unroll
    for (int j = 0; j < 8; j++) {
        w0[j] = fcW[0 * HH + lane * 8 + j];
        w1[j] = fcW[1 * HH + lane * 8 + j];
        w2[j] = fcW[2 * HH + lane * 8 + j];
    }
    const float c0 = fcb[0], c1 = fcb[1], c2 = fcb[2];

    for (int row = wid; row < BB * TT; row += nw) {
        const float* hr = hidden + (size_t)row * HH + lane * 8;
        float v[8];
        *(float4*)&v[0] = *(const float4*)hr;
        *(float4*)&v[4] = *(const float4*)(hr + 4);
        float s0 = 0.f, s1 = 0.f, s2 = 0.f;
        #pragma unroll
        for (int j = 0; j < 8; j++) {
            s0 += v[j] * w0[j];
            s1 += v[j] * w1[j];
            s2 += v[j] * w2[j];
        }
        #pragma unroll
        for (int off = 1; off < 64; off <<= 1) {
            s0 += __shfl_xor(s0, off);
            s1 += __shfl_xor(s1, off);
            s2 += __shfl_xor(s2, off);
        }
        if (lane == 0) {
            float* o = out + (size_t)row * CC;
            o[0] = s0 + c0; o[1] = s1 + c1; o[2] = s2 + c2;
        }
    }
}

extern "C" void kernel_launch(void* const* d_in, const int* in_sizes, int n_in,
                              void* d_out, int out_size, void* d_ws, size_t ws_size,
                              hipStream_t stream) {
    (void)in_sizes; (void)n_in; (void)out_size; (void)ws_size;
    const float* x   = (const float*)d_in[0];
    const float* W   = (const float*)d_in[1];
    const float* P   = (const float*)d_in[2];
    const float* bv  = (const float*)d_in[3];
    const float* Wz  = (const float*)d_in[4];
    const float* Pz  = (const float*)d_in[5];
    const float* bz  = (const float*)d_in[6];
    const float* fcW = (const float*)d_in[7];
    const float* fcb = (const float*)d_in[8];

    float* out    = (float*)d_out;
    float* hidden = out + (size_t)BB * TT * CC;

    int* cnt       = (int*)d_ws;                              // 8*1025*4 = 32.8KB (zeroed below)
    unsigned* Rbuf = (unsigned*)((char*)d_ws + 65536);        // 2*128*256 u32 = 256KB

    hipMemsetAsync(d_ws, 0, 65536, stream);
    hipLaunchKernelGGL(rnn_persist, dim3(NG * NCH), dim3(256), 0, stream,
                       x, W, P, bv, Wz, Pz, bz, hidden, Rbuf, cnt);
    hipLaunchKernelGGL(fc_kernel, dim3(256), dim3(256), 0, stream,
                       hidden, fcW, fcb, out);
}

// Round 2
// 2319.579 us; speedup vs baseline: 2.7826x; 2.7826x over previous
//
#include <hip/hip_runtime.h>
#include <hip/hip_bf16.h>

// Problem constants
#define BB 128
#define TT 1024
#define DD 3
#define HH 512
#define CC 3

#define NG 8      // batch groups
#define NCH 16    // h-chunks per group
#define MB 16     // batch rows per group
#define HC 32     // h columns per chunk

typedef __attribute__((ext_vector_type(8))) __bf16 bf16x8;
typedef __attribute__((ext_vector_type(4))) float f32x4;

// Persistent RNN. 128 blocks x 256 threads, ~87KB LDS -> 1 block/CU, all
// co-resident. Sync via per-chunk monotonic tag words (relaxed agent-scope
// stores; ordering from __syncthreads' vmcnt(0) drain). NO acquire/release
// C++ atomics -> no per-step L2 writeback/invalidate storms (the R1 6us/step
// killer). Consumer state loads bypass L1/L2 via sc0 sc1 asm loads.
__global__ __launch_bounds__(256, 1) void rnn_persist(
    const float* __restrict__ x,    // [B][T][D]
    const float* __restrict__ W,    // [H][H]
    const float* __restrict__ P,    // [H][D]
    const float* __restrict__ bv,   // [H]
    const float* __restrict__ Wz,   // [H][H]
    const float* __restrict__ Pz,   // [H][D]
    const float* __restrict__ bz,   // [H]
    float* __restrict__ hidden,     // [B][T][H] (inside d_out)
    unsigned* __restrict__ Rbuf,    // [2][B][H/2] u32 = bf16 pairs (d_ws)
    unsigned* __restrict__ tag)     // [NG][NCH] monotonic step tags (d_ws, zeroed)
{
    __shared__ __align__(16) __bf16 Wl[64][520];  // rows 0..31 Wz, 32..63 W (pitch 520)
    __shared__ __align__(16) __bf16 Ra[16][520];  // staged state S_t
    __shared__ float pre[16][68];                 // MFMA out: [batch][col], col 0..31 z, 32..63 cand

    const int tid = threadIdx.x;
    const int bid = blockIdx.x;
    const int g   = bid & 7;         // batch group
    const int ch  = bid >> 3;        // h chunk
    const int h0  = ch * HC;
    const int b0  = g * MB;

    // ---- one-time: weights -> LDS bf16 ----
    for (int idx = tid; idx < 64 * 512; idx += 256) {
        int row = idx >> 9, col = idx & 511;
        float v = (row < 32) ? Wz[(h0 + row) * HH + col]
                             : W[(h0 + row - 32) * HH + col];
        Wl[row][col] = (__bf16)v;
    }

    const int lane = tid & 63;
    const int wv   = tid >> 6;       // wave -> output cols [wv*16, wv*16+16)
    const int frow = lane & 15;
    const int q    = lane >> 4;
    const int eb   = tid >> 4;       // elementwise batch row 0..15
    const int ehp  = tid & 15;       // elementwise h-pair 0..15

    // per-thread small weights in registers (cols hl0, hl1 of this chunk)
    const int hl0 = 2 * ehp, hl1 = hl0 + 1;
    const int hg0 = h0 + hl0, hg1 = h0 + hl1;
    const float pzw00 = Pz[hg0*3+0], pzw01 = Pz[hg0*3+1], pzw02 = Pz[hg0*3+2];
    const float pzw10 = Pz[hg1*3+0], pzw11 = Pz[hg1*3+1], pzw12 = Pz[hg1*3+2];
    const float pvw00 = (hg0 < HH/2) ? P[hg0*3+0] : 0.f;
    const float pvw01 = (hg0 < HH/2) ? P[hg0*3+1] : 0.f;
    const float pvw02 = (hg0 < HH/2) ? P[hg0*3+2] : 0.f;
    const float pvw10 = (hg1 < HH/2) ? P[hg1*3+0] : 0.f;
    const float pvw11 = (hg1 < HH/2) ? P[hg1*3+1] : 0.f;
    const float pvw12 = (hg1 < HH/2) ? P[hg1*3+2] : 0.f;
    const float bzr0 = bz[hg0], bzr1 = bz[hg1];
    const float bvr0 = bv[hg0], bvr1 = bv[hg1];

    // init S_0 = 0 into buf0 (MALL-direct relaxed atomic stores)
    {
        unsigned* dst0 = Rbuf + (size_t)(b0 + eb) * (HH / 2) + ch * 16 + ehp;
        __hip_atomic_store(dst0, 0u, __ATOMIC_RELAXED, __HIP_MEMORY_SCOPE_AGENT);
    }
    __syncthreads();   // waits vmcnt(0): S_0 stores acked at MALL before tag
    if (tid == 0)
        __hip_atomic_store(&tag[g * 16 + ch], 1u, __ATOMIC_RELAXED, __HIP_MEMORY_SCOPE_AGENT);

    // preload B fragments (weights) into registers: 16 x bf16x8 = 64 VGPRs
    bf16x8 Bfrag[16];
    #pragma unroll
    for (int ks = 0; ks < 16; ks++)
        Bfrag[ks] = *(const bf16x8*)&Wl[wv * 16 + frow][ks * 32 + q * 8];

    float rs0 = 0.f, rs1 = 0.f;      // f32 state for (eb, hl0/hl1) lives in regs
    const float* xptr = x + (size_t)(b0 + eb) * TT * DD;

    for (int t = 0; t < TT; t++) {
        float x0 = xptr[0], x1 = xptr[1], x2 = xptr[2];   // overlaps the poll
        xptr += DD;

        // poll: all 16 chunk tags >= t+1 (one vector load per spin, no RMW)
        if (tid < 64) {
            unsigned want = (unsigned)(t + 1);
            const unsigned* tp = tag + g * 16 + (tid & 15);
            while (true) {
                unsigned v = (tid < 16)
                    ? __hip_atomic_load(tp, __ATOMIC_RELAXED, __HIP_MEMORY_SCOPE_AGENT)
                    : 0xFFFFFFFFu;
                if (__all((int)(v >= want))) break;
            }
        }
        __syncthreads();

        // stage S_t (16KB) from MALL, bypassing L1/L2 (sc0 sc1)
        {
            const uint4* p0 = (const uint4*)(Rbuf + (size_t)(t & 1) * BB * (HH / 2)
                                             + (size_t)b0 * (HH / 2)) + tid;
            const uint4* p1 = p0 + 256;
            const uint4* p2 = p0 + 512;
            const uint4* p3 = p0 + 768;
            uint4 A0, A1, A2, A3;
            asm volatile(
                "global_load_dwordx4 %0, %4, off sc0 sc1\n\t"
                "global_load_dwordx4 %1, %5, off sc0 sc1\n\t"
                "global_load_dwordx4 %2, %6, off sc0 sc1\n\t"
                "global_load_dwordx4 %3, %7, off sc0 sc1\n\t"
                "s_waitcnt vmcnt(0)"
                : "=&v"(A0), "=&v"(A1), "=&v"(A2), "=&v"(A3)
                : "v"(p0), "v"(p1), "v"(p2), "v"(p3)
                : "memory");
            char* rb = (char*)&Ra[0][0];
            const int co = (tid & 63) * 16;
            *(uint4*)(rb + (wv     ) * 1040 + co) = A0;   // row = wv + 4i
            *(uint4*)(rb + (wv +  4) * 1040 + co) = A1;
            *(uint4*)(rb + (wv +  8) * 1040 + co) = A2;
            *(uint4*)(rb + (wv + 12) * 1040 + co) = A3;
        }
        __syncthreads();

        // MFMA: D[m][n] = sum_k S[m][k] * Wl[n][k]; A from LDS, B from regs
        f32x4 acc = {0.f, 0.f, 0.f, 0.f};
        #pragma unroll
        for (int ks = 0; ks < 16; ks++) {
            bf16x8 af = *(const bf16x8*)&Ra[frow][ks * 32 + q * 8];
            acc = __builtin_amdgcn_mfma_f32_16x16x32_bf16(af, Bfrag[ks], acc, 0, 0, 0);
        }
        #pragma unroll
        for (int r = 0; r < 4; r++)
            pre[q * 4 + r][wv * 16 + frow] = acc[r];   // row=m (batch), col=n
        __syncthreads();

        // gates + state update (state in registers)
        float pz0 = pre[eb][hl0]      + x0*pzw00 + x1*pzw01 + x2*pzw02 + bzr0;
        float pz1 = pre[eb][hl1]      + x0*pzw10 + x1*pzw11 + x2*pzw12 + bzr1;
        float pv0 = pre[eb][32 + hl0] + x0*pvw00 + x1*pvw01 + x2*pvw02 + bvr0;
        float pv1 = pre[eb][32 + hl1] + x0*pvw10 + x1*pvw11 + x2*pvw12 + bvr1;
        float z0 = 1.f / (1.f + __expf(-pz0));
        float z1 = 1.f / (1.f + __expf(-pz1));
        float c0 = 1.f / (1.f + __expf(-pv0));
        float c1 = 1.f / (1.f + __expf(-pv1));
        rs0 = (1.f - z0) * rs0 + z0 * c0;
        rs1 = (1.f - z1) * rs1 + z1 * c1;

        // publish S_{t+1} (bf16 pair, MALL-direct)
        union { __bf16 h[2]; unsigned u; } pk;
        pk.h[0] = (__bf16)rs0; pk.h[1] = (__bf16)rs1;
        unsigned* dst = Rbuf + (size_t)((t + 1) & 1) * BB * (HH / 2)
                        + (size_t)(b0 + eb) * (HH / 2) + ch * 16 + ehp;
        __hip_atomic_store(dst, pk.u, __ATOMIC_RELAXED, __HIP_MEMORY_SCOPE_AGENT);
        // hidden output (f32 exact state)
        float2 hv; hv.x = rs0; hv.y = rs1;
        *(float2*)&hidden[((size_t)(b0 + eb) * TT + t) * HH + h0 + hl0] = hv;

        __syncthreads();   // vmcnt(0) drain for ALL threads' stores -> then tag
        if (tid == 0)
            __hip_atomic_store(&tag[g * 16 + ch], (unsigned)(t + 2),
                               __ATOMIC_RELAXED, __HIP_MEMORY_SCOPE_AGENT);
    }
}

// out[b][t][c] = hidden[b][t][:] . fc_W[c][:] + fc_b[c]; latency-hidden via
// 2-deep row prefetch, grid 1024 (R1 version was 268us: latency-bound).
__global__ __launch_bounds__(256) void fc_kernel(
    const float* __restrict__ hidden, const float* __restrict__ fcW,
    const float* __restrict__ fcb, float* __restrict__ out)
{
    const int lane = threadIdx.x & 63;
    const int wid  = (blockIdx.x * blockDim.x + threadIdx.x) >> 6;
    const int nw   = (gridDim.x * blockDim.x) >> 6;
    const int NR   = BB * TT;

    float w0[8], w1[8], w2[8];
    #pragma unroll
    for (int j = 0; j < 8; j++) {
        w0[j] = fcW[0 * HH + lane * 8 + j];
        w1[j] = fcW[1 * HH + lane * 8 + j];
        w2[j] = fcW[2 * HH + lane * 8 + j];
    }
    const float c0 = fcb[0], c1 = fcb[1], c2 = fcb[2];

    int row = wid;
    float4 va, vb;
    if (row < NR) {
        const float* hr = hidden + (size_t)row * HH + lane * 8;
        va = *(const float4*)hr;
        vb = *(const float4*)(hr + 4);
    }
    while (row < NR) {
        int nrow = row + nw;
        float4 na, nb;
        if (nrow < NR) {
            const float* hr = hidden + (size_t)nrow * HH + lane * 8;
            na = *(const float4*)hr;
            nb = *(const float4*)(hr + 4);
        }
        float s0 = va.x*w0[0] + va.y*w0[1] + va.z*w0[2] + va.w*w0[3]
                 + vb.x*w0[4] + vb.y*w0[5] + vb.z*w0[6] + vb.w*w0[7];
        float s1 = va.x*w1[0] + va.y*w1[1] + va.z*w1[2] + va.w*w1[3]
                 + vb.x*w1[4] + vb.y*w1[5] + vb.z*w1[6] + vb.w*w1[7];
        float s2 = va.x*w2[0] + va.y*w2[1] + va.z*w2[2] + va.w*w2[3]
                 + vb.x*w2[4] + vb.y*w2[5] + vb.z*w2[6] + vb.w*w2[7];
        #pragma unroll
        for (int off = 1; off < 64; off <<= 1) {
            s0 += __shfl_xor(s0, off);
            s1 += __shfl_xor(s1, off);
            s2 += __shfl_xor(s2, off);
        }
        if (lane == 0) {
            float* o = out + (size_t)row * CC;
            o[0] = s0 + c0; o[1] = s1 + c1; o[2] = s2 + c2;
        }
        row = nrow; va = na; vb = nb;
    }
}

extern "C" void kernel_launch(void* const* d_in, const int* in_sizes, int n_in,
                              void* d_out, int out_size, void* d_ws, size_t ws_size,
                              hipStream_t stream) {
    (void)in_sizes; (void)n_in; (void)out_size; (void)ws_size;
    const float* x   = (const float*)d_in[0];
    const float* W   = (const float*)d_in[1];
    const float* P   = (const float*)d_in[2];
    const float* bv  = (const float*)d_in[3];
    const float* Wz  = (const float*)d_in[4];
    const float* Pz  = (const float*)d_in[5];
    const float* bz  = (const float*)d_in[6];
    const float* fcW = (const float*)d_in[7];
    const float* fcb = (const float*)d_in[8];

    float* out    = (float*)d_out;
    float* hidden = out + (size_t)BB * TT * CC;

    unsigned* tag  = (unsigned*)d_ws;                         // 8*16 u32, zeroed below
    unsigned* Rbuf = (unsigned*)((char*)d_ws + 4096);         // 2*128*256 u32 = 256KB

    hipMemsetAsync(d_ws, 0, 4096, stream);
    hipLaunchKernelGGL(rnn_persist, dim3(NG * NCH), dim3(256), 0, stream,
                       x, W, P, bv, Wz, Pz, bz, hidden, Rbuf, tag);
    hipLaunchKernelGGL(fc_kernel, dim3(1024), dim3(256), 0, stream,
                       hidden, fcW, fcb, out);
}